// Round 1
// baseline (55.101 us; speedup 1.0000x reference)
//
#include <hip/hip_runtime.h>
#include <math.h>

namespace {

constexpr int kBS      = 512;
constexpr int kNA      = 3;
constexpr int kGS      = 13;
constexpr int kAttrs   = 85;           // 5 + 80 classes
constexpr int kSpatial = kGS * kGS;    // 169
constexpr int kCells   = kBS * kNA * kSpatial;  // 259,584
constexpr float kStrideF = 32.0f;      // 416 / 13

__device__ __forceinline__ float fsigmoid(float x) {
    return 1.0f / (1.0f + __expf(-x));
}

__global__ __launch_bounds__(256) void yolo_head_kernel(const float* __restrict__ x,
                                                        float* __restrict__ out) {
    const int cell = blockIdx.x * 256 + threadIdx.x;
    if (cell >= kCells) return;

    const int s  = cell % kSpatial;   // i*13 + j
    const int ba = cell / kSpatial;   // b*3 + a
    const int a  = ba % kNA;

    // x[b, a*85 + c, i, j]  ->  base + c*169, strided per attribute,
    // coalesced across lanes (consecutive s).
    const float* __restrict__ xp = x + (size_t)ba * kAttrs * kSpatial + s;

    float v[kAttrs];
#pragma unroll
    for (int c = 0; c < kAttrs; ++c) {
        v[c] = xp[(size_t)c * kSpatial];
    }

    const float jf = (float)(s % kGS);   // grid_x
    const float if_ = (float)(s / kGS);  // grid_y

    // anchor_w/stride * stride == anchor (pixels)
    const float aw = (a == 0) ? 116.0f : (a == 1) ? 156.0f : 373.0f;
    const float ah = (a == 0) ?  90.0f : (a == 1) ? 198.0f : 326.0f;

    const float bx   = (fsigmoid(v[0]) + jf) * kStrideF;
    const float by   = (fsigmoid(v[1]) + if_) * kStrideF;
    const float bw   = __expf(v[2]) * aw;
    const float bh   = __expf(v[3]) * ah;
    const float conf = fsigmoid(v[4]);

    // softmax over the 80 class logits (v[5..85))
    float m = v[5];
#pragma unroll
    for (int c = 6; c < kAttrs; ++c) m = fmaxf(m, v[c]);
    float sum = 0.0f;
#pragma unroll
    for (int c = 5; c < kAttrs; ++c) {
        const float e = __expf(v[c] - m);
        v[c] = e;
        sum += e;
    }
    const float inv = 1.0f / sum;

    // out[cell, c] — 85 contiguous floats per cell
    float* __restrict__ op = out + (size_t)cell * kAttrs;
    op[0] = bx;
    op[1] = by;
    op[2] = bw;
    op[3] = bh;
    op[4] = conf;
#pragma unroll
    for (int c = 5; c < kAttrs; ++c) op[c] = v[c] * inv;
}

}  // namespace

extern "C" void kernel_launch(void* const* d_in, const int* in_sizes, int n_in,
                              void* d_out, int out_size, void* d_ws, size_t ws_size,
                              hipStream_t stream) {
    const float* x = (const float*)d_in[0];
    float* out = (float*)d_out;
    const int blocks = (kCells + 255) / 256;  // 1014
    yolo_head_kernel<<<blocks, 256, 0, stream>>>(x, out);
}

// Round 2
// 37.482 us; speedup vs baseline: 1.4701x; 1.4701x over previous
//
#include <hip/hip_runtime.h>
#include <math.h>

namespace {

constexpr int kBS      = 512;
constexpr int kNA      = 3;
constexpr int kGS      = 13;
constexpr int kAttrs   = 85;           // 5 + 80 classes
constexpr int kSpatial = kGS * kGS;    // 169
constexpr int kCells   = kBS * kNA * kSpatial;  // 259,584
constexpr float kStrideF = 32.0f;      // 416 / 13

constexpr int kBlockThreads = 128;               // 2 waves
constexpr int kCellsPerBlock = kBlockThreads;    // 1 cell per thread
constexpr int kSmemFloats = kCellsPerBlock * kAttrs;   // 10,880 floats = 43,520 B
constexpr int kSmemFloat4 = kSmemFloats / 4;           // 2,720

__device__ __forceinline__ float fsigmoid(float x) {
    return 1.0f / (1.0f + __expf(-x));
}

__global__ __launch_bounds__(kBlockThreads) void yolo_head_kernel(const float* __restrict__ x,
                                                                  float* __restrict__ out) {
    __shared__ float smem[kSmemFloats];

    const int tid  = threadIdx.x;
    const int cell = blockIdx.x * kCellsPerBlock + tid;   // grid sized exactly

    const int s  = cell % kSpatial;   // i*13 + j
    const int ba = cell / kSpatial;   // b*3 + a
    const int a  = ba % kNA;

    // x[b, a*85 + c, i, j] -> base + c*169; lanes have consecutive s -> coalesced.
    const float* __restrict__ xp = x + (size_t)ba * kAttrs * kSpatial + s;

    float v[kAttrs];
#pragma unroll
    for (int c = 0; c < kAttrs; ++c) {
        v[c] = xp[(size_t)c * kSpatial];
    }

    const float jf  = (float)(s % kGS);   // grid_x
    const float if_ = (float)(s / kGS);   // grid_y

    const float aw = (a == 0) ? 116.0f : (a == 1) ? 156.0f : 373.0f;
    const float ah = (a == 0) ?  90.0f : (a == 1) ? 198.0f : 326.0f;

    float* __restrict__ sp = smem + tid * kAttrs;  // lane stride 85 words: gcd(85,32)=1 -> conflict-free

    sp[0] = (fsigmoid(v[0]) + jf) * kStrideF;     // bx
    sp[1] = (fsigmoid(v[1]) + if_) * kStrideF;    // by
    sp[2] = __expf(v[2]) * aw;                    // bw
    sp[3] = __expf(v[3]) * ah;                    // bh
    sp[4] = fsigmoid(v[4]);                       // conf

    // softmax over 80 class logits
    float m = v[5];
#pragma unroll
    for (int c = 6; c < kAttrs; ++c) m = fmaxf(m, v[c]);
    float sum = 0.0f;
#pragma unroll
    for (int c = 5; c < kAttrs; ++c) {
        const float e = __expf(v[c] - m);
        v[c] = e;
        sum += e;
    }
    const float inv = 1.0f / sum;
#pragma unroll
    for (int c = 5; c < kAttrs; ++c) sp[c] = v[c] * inv;

    __syncthreads();

    // Cooperative coalesced copy: block's output region is contiguous.
    // blockBase bytes = blockIdx.x * 43,520 -> 16B aligned.
    float4* __restrict__ out4 = (float4*)(out + (size_t)blockIdx.x * kSmemFloats);
    const float4* __restrict__ s4 = (const float4*)smem;
#pragma unroll 4
    for (int t = tid; t < kSmemFloat4; t += kBlockThreads) {
        out4[t] = s4[t];
    }
}

}  // namespace

extern "C" void kernel_launch(void* const* d_in, const int* in_sizes, int n_in,
                              void* d_out, int out_size, void* d_ws, size_t ws_size,
                              hipStream_t stream) {
    const float* x = (const float*)d_in[0];
    float* out = (float*)d_out;
    const int blocks = kCells / kCellsPerBlock;  // 2028 exactly
    yolo_head_kernel<<<blocks, kBlockThreads, 0, stream>>>(x, out);
}